// Round 19
// baseline (9171.008 us; speedup 1.0000x reference)
//
#include <hip/hip_runtime.h>
#include <hip/hip_bf16.h>
#include <cstdint>
#include <cstddef>

#define DEV __device__ __forceinline__

typedef _Float16 h2v __attribute__((ext_vector_type(2)));
typedef unsigned u4v __attribute__((ext_vector_type(4)));

DEV float sigmoidf_(float x) { return 1.0f / (1.0f + __expf(-x)); }
DEV float tanhf_(float x) {
    float e = __expf(2.0f * x);
    return 1.0f - 2.0f / (e + 1.0f);
}
DEV h2v asH2(unsigned x) { union { unsigned u; h2v h; } c; c.u = x; return c.h; }

// LDS-only barrier: does NOT drain vmcnt; global prefetch/stores stay in flight.
#define LDS_BARRIER() asm volatile("s_waitcnt lgkmcnt(0)\n\ts_barrier" ::: "memory")

// ---------------------------------------------------------------------------
// Pack 10 matrices (256x64 each) to f16 pairs, split-K layout:
//   dst[m][half][qs][u][w]   (qs = q*4+s: gate q, slice s; w = word 0..3)
// m: 0-2 l1Whh, 3-5 l2Whh, 6-7 Wih12 (l1 layers 1,2), 8-9 l2Wih layers 1,2.
// ---------------------------------------------------------------------------
__global__ __launch_bounds__(256) void pack_w(
    const float* __restrict__ l1Whh, const float* __restrict__ l2Whh,
    const float* __restrict__ Wih12, const float* __restrict__ l2Wih,
    unsigned* __restrict__ wP)
{
    int idx = blockIdx.x * 256 + threadIdx.x;   // 10*8192 = 81920
    int m = idx >> 13;
    int rem = idx & 8191;
    int half = rem >> 12;
    int qs = (rem >> 8) & 15;
    int u = (rem >> 2) & 63;
    int w = rem & 3;
    int q = qs >> 2, s = qs & 3;
    int jp = 16 * half + 4 * s + w;

    const float* W;
    if (m < 3)      W = l1Whh + (size_t)m * 16384;
    else if (m < 6) W = l2Whh + (size_t)(m - 3) * 16384;
    else if (m < 8) W = Wih12 + (size_t)(m - 6) * 16384;
    else            W = l2Wih + (size_t)(m - 7) * 16384;   // layers 1,2

    const float* row = W + (size_t)(q * 64 + u) * 64;
    union { h2v h; unsigned u32; } c;
    c.h = (h2v){(_Float16)row[2 * jp], (_Float16)row[2 * jp + 1]};
    wP[idx] = c.u32;
}

// ---------------------------------------------------------------------------
// Input projection (layer 0 of each stack only): xg[b,t,u*4+q] unit-major.
// ---------------------------------------------------------------------------
__global__ __launch_bounds__(256) void proj_kernel(
    const float* __restrict__ x, const float* __restrict__ Wih,
    const float* __restrict__ bias, const float* __restrict__ gate,
    float* __restrict__ xg, int D, int T)
{
    __shared__ float xS[16 * 64];
    int tb = T / 16;
    int b  = blockIdx.x / tb;
    int t0 = (blockIdx.x % tb) * 16;
    int tid = threadIdx.x;

    int n = 16 * D;
    for (int e = tid; e < n; e += 256) {
        int t = e / D;
        int i = e - t * D;
        float v = x[((size_t)(b * T + t0 + t)) * D + i];
        if (gate) v += gate[b * T + t0 + t];
        xS[t * D + i] = v;
    }
    __syncthreads();

    int g = tid;
    float acc[16];
    float bg = bias[g];
#pragma unroll
    for (int t = 0; t < 16; t++) acc[t] = bg;

    const float* wr = Wih + (size_t)g * D;
    for (int i = 0; i < D; i++) {
        float w = wr[i];
#pragma unroll
        for (int t = 0; t < 16; t++) acc[t] += xS[t * D + i] * w;
    }

    float* og = xg + ((size_t)(b * T + t0)) * 256 + (g & 63) * 4 + (g >> 6);
#pragma unroll
    for (int t = 0; t < 16; t++) og[(size_t)t * 256] = acc[t];
}

// ---------------------------------------------------------------------------
// Per-wave matrix slice base (10-wave mapping, shared by copy + compute).
// ---------------------------------------------------------------------------
DEV const u4v* slice_base(const unsigned* whhP, const unsigned* wihP, int w) {
    int layer = (w < 2) ? 0 : (w < 6 ? 1 : 2);
    int base  = (layer == 0) ? 0 : (layer == 1 ? 2 : 6);
    int idx   = w - base;
    bool isWih = (layer > 0) && (idx >= 2);
    int half  = isWih ? (idx - 2) : idx;
    return isWih ? (const u4v*)wihP + (size_t)(layer - 1) * 2048 + (size_t)half * 1024
                 : (const u4v*)whhP + (size_t)layer * 2048 + (size_t)half * 1024;
}

// ---------------------------------------------------------------------------
// Pipelined 3-layer LSTM scan v19: ONE block per batch, TEN waves (R12 map).
// HOMOGENEOUS per-wave weight source (R18's mistake: each wave used both
// pipes serially in its in-order stream, so L1+LDS added instead of
// overlapped):
//   waves 0-4: named-SSA register quads; the allocator remats them -> each
//     streams 16KB/tick from L1 (5 waves = 80KB/tick ~ 1250cyc on TA pipe);
//   waves 5-9: 16 quads/tick streamed from an 80KB static LDS image
//     (80 ds_read_b128/tick ~ 960cyc + ~300 exch/h overhead on LDS pipe).
// Different waves occupy different pipes -> true overlap:
// tick ~ max(1250, 1260) ~ 1300cyc vs R12's serial ~2250.
// (Register-war ledger: residency needs W*(grant-30)>=640; max over wave
// counts is 544 -- impossible. Streaming is the only option; balance pipes.)
// ---------------------------------------------------------------------------
__global__ __launch_bounds__(640)
void scan3_kernel(
    const float* __restrict__ xg, const unsigned* __restrict__ whhP,
    const unsigned* __restrict__ wihP, const float* __restrict__ bvec,
    const float* __restrict__ h0, const float* __restrict__ c0,
    float* __restrict__ Hout, int T)
{
    __shared__ __align__(16) _Float16 hL[3][64];   // per-layer h (f16)
    __shared__ __align__(16) float4 exch[10][64];  // per-wave partials
    __shared__ __align__(16) u4v wS[5 * 16 * 64];  // 80KB: waves 5-9 slices
    int b = blockIdx.x;
    int tid = threadIdx.x;
    int wv = tid >> 6, u = tid & 63;

    int layer = (wv < 2) ? 0 : (wv < 6 ? 1 : 2);
    int base  = (layer == 0) ? 0 : (layer == 1 ? 2 : 6);
    int idx   = wv - base;                 // 0..1 (L0) or 0..3 (L1,L2)
    bool isWih = (layer > 0) && (idx >= 2);
    bool isRed = (idx == 0);
    int nsrc  = (layer == 0) ? 2 : 4;

    // stage waves 5..9's full slices (16 quads each) into LDS, once
    for (int e = tid; e < 5 * 16 * 64; e += 640) {
        int ws = e >> 10, j = (e >> 6) & 15, uu = e & 63;
        wS[e] = slice_base(whhP, wihP, 5 + ws)[j * 64 + uu];
    }

    // waves 0..4: 16 named-SSA register quads (pin; remat -> L1 stream)
    const u4v* wp = slice_base(whhP, wihP, wv) + u;
    u4v rI0, rI1, rI2, rI3, rF0, rF1, rF2, rF3;
    u4v rG0, rG1, rG2, rG3, rO0, rO1, rO2, rO3;
    if (wv < 5) {
        rI0 = wp[0 * 64];  rI1 = wp[1 * 64];  rI2 = wp[2 * 64];  rI3 = wp[3 * 64];
        rF0 = wp[4 * 64];  rF1 = wp[5 * 64];  rF2 = wp[6 * 64];  rF3 = wp[7 * 64];
        rG0 = wp[8 * 64];  rG1 = wp[9 * 64];  rG2 = wp[10 * 64]; rG3 = wp[11 * 64];
        rO0 = wp[12 * 64]; rO1 = wp[13 * 64]; rO2 = wp[14 * 64]; rO3 = wp[15 * 64];
        asm volatile("" : "+v"(rI0), "+v"(rI1), "+v"(rI2), "+v"(rI3),
                          "+v"(rF0), "+v"(rF1), "+v"(rF2), "+v"(rF3));
        asm volatile("" : "+v"(rG0), "+v"(rG1), "+v"(rG2), "+v"(rG3),
                          "+v"(rO0), "+v"(rO1), "+v"(rO2), "+v"(rO3));
    }

    // reducer state: c, bias (L0 bias lives in xg)
    float c = 0.f;
    float4 bl = make_float4(0.f, 0.f, 0.f, 0.f);
    if (isRed) {
        c = c0[layer * 128 + b * 64 + u];
        hL[layer][u] = (_Float16)h0[layer * 128 + b * 64 + u];
        if (layer > 0) {
            const float* bb = bvec + layer * 256;
            bl = make_float4(bb[u], bb[64 + u], bb[128 + u], bb[192 + u]);
        }
    }
    __syncthreads();

    // h source: Whh waves read own layer; Wih waves read layer-1.
    int half = isWih ? (idx - 2) : idx;
    const u4v* hsrc = (const u4v*)(&hL[isWih ? layer - 1 : layer][0]) + half * 4;
    const u4v* wsl  = wS + (wv - 5) * 1024 + u;   // LDS quad j at wsl[j*64]

    // x preacts: wave 0 only, consume-then-reload 2-deep
    const float4* xp = (const float4*)(xg + (size_t)b * T * 256) + u;
    float4 xb[2];
    xb[0] = xb[1] = make_float4(0.f, 0.f, 0.f, 0.f);
    if (wv == 0) {
        xb[0] = xp[0];
        xb[1] = xp[64];
    }

    float* hout = Hout + (size_t)b * T * 64 + u;

#define FD(HP, WV, ACC) ACC = __builtin_amdgcn_fdot2(asH2(HP), asH2(WV), ACC, false)
#define DOT4(HP, WQ, ACC) { FD(HP.x, WQ.x, ACC); FD(HP.y, WQ.y, ACC); \
                            FD(HP.z, WQ.z, ACC); FD(HP.w, WQ.w, ACC); }

    int Tt = T + 4;   // pipeline drain (multiple of 2)
    for (int t2 = 0; t2 < Tt; t2 += 2) {
#pragma unroll
        for (int k = 0; k < 2; k++) {
            int tick = t2 + k;

            float aI, aF, aG, aO;
            if (wv == 0) {
                float4 x = xb[k];
                aI = x.x; aF = x.y; aG = x.z; aO = x.w;
                int tp = tick + 2; if (tp > T - 1) tp = T - 1;
                xb[k] = xp[(size_t)tp * 64];   // wait lands 2 ticks later
            } else {
                aI = aF = aG = aO = 0.f;
            }

            // h quads once, reused by all four gates
            u4v hp0 = hsrc[0], hp1 = hsrc[1], hp2 = hsrc[2], hp3 = hsrc[3];

            if (wv < 5) {
                // L1/register path (remat streams from L1 on the TA pipe)
                DOT4(hp0, rI0, aI) DOT4(hp1, rI1, aI) DOT4(hp2, rI2, aI) DOT4(hp3, rI3, aI)
                DOT4(hp0, rF0, aF) DOT4(hp1, rF1, aF) DOT4(hp2, rF2, aF) DOT4(hp3, rF3, aF)
                DOT4(hp0, rG0, aG) DOT4(hp1, rG1, aG) DOT4(hp2, rG2, aG) DOT4(hp3, rG3, aG)
                DOT4(hp0, rO0, aO) DOT4(hp1, rO1, aO) DOT4(hp2, rO2, aO) DOT4(hp3, rO3, aO)
            } else {
                // LDS-streamed path (LDS pipe only)
                u4v q0, q1, q2, q3;
                q0 = wsl[0 * 64];  q1 = wsl[1 * 64];
                q2 = wsl[2 * 64];  q3 = wsl[3 * 64];
                DOT4(hp0, q0, aI) DOT4(hp1, q1, aI) DOT4(hp2, q2, aI) DOT4(hp3, q3, aI)
                q0 = wsl[4 * 64];  q1 = wsl[5 * 64];
                q2 = wsl[6 * 64];  q3 = wsl[7 * 64];
                DOT4(hp0, q0, aF) DOT4(hp1, q1, aF) DOT4(hp2, q2, aF) DOT4(hp3, q3, aF)
                q0 = wsl[8 * 64];  q1 = wsl[9 * 64];
                q2 = wsl[10 * 64]; q3 = wsl[11 * 64];
                DOT4(hp0, q0, aG) DOT4(hp1, q1, aG) DOT4(hp2, q2, aG) DOT4(hp3, q3, aG)
                q0 = wsl[12 * 64]; q1 = wsl[13 * 64];
                q2 = wsl[14 * 64]; q3 = wsl[15 * 64];
                DOT4(hp0, q0, aO) DOT4(hp1, q1, aO) DOT4(hp2, q2, aO) DOT4(hp3, q3, aO)
            }

            exch[wv][u] = make_float4(aI, aF, aG, aO);
            LDS_BARRIER();   // partials visible

            if (isRed) {
                int tcur = tick - layer;
                if ((unsigned)tcur < (unsigned)T) {
                    float sI = aI + bl.x, sF = aF + bl.y;
                    float sG = aG + bl.z, sO = aO + bl.w;
                    for (int j = 1; j < nsrc; j++) {
                        float4 p = exch[base + j][u];
                        sI += p.x; sF += p.y; sG += p.z; sO += p.w;
                    }
                    c = sigmoidf_(sF) * c + sigmoidf_(sI) * tanhf_(sG);
                    float h = sigmoidf_(sO) * tanhf_(c);
                    hL[layer][u] = (_Float16)h;
                    if (layer == 2) hout[(size_t)tcur * 64] = h;
                }
            }
            LDS_BARRIER();   // h writes visible; WAR on exch protected
        }
    }
#undef FD
#undef DOT4
}

// ---------------------------------------------------------------------------
// Hc[b, {max,mean,std(ddof=1)}, t] over hidden dim (64). One wave per (b,t).
// ---------------------------------------------------------------------------
__global__ __launch_bounds__(256) void stats_kernel(
    const float* __restrict__ H, float* __restrict__ Hc, int T)
{
    int wid = threadIdx.x >> 6, lane = threadIdx.x & 63;
    int bt = blockIdx.x * 4 + wid;
    int b = bt / T, t = bt - b * T;

    float x = H[(size_t)bt * 64 + lane];
    float mx = x, sm = x;
#pragma unroll
    for (int m = 32; m >= 1; m >>= 1) {
        mx = fmaxf(mx, __shfl_xor(mx, m));
        sm += __shfl_xor(sm, m);
    }
    float mean = sm * (1.0f / 64.0f);
    float d = x - mean;
    float ss = d * d;
#pragma unroll
    for (int m = 32; m >= 1; m >>= 1) ss += __shfl_xor(ss, m);
    float sd = sqrtf(ss * (1.0f / 63.0f));

    if (lane == 0) {
        float* o = Hc + (size_t)b * 3 * T;
        o[0 * T + t] = mx;
        o[1 * T + t] = mean;
        o[2 * T + t] = sd;
    }
}

// ---------------------------------------------------------------------------
// Middle conv/BN chain, single workgroup (1024 threads).
// ---------------------------------------------------------------------------
template <int CIN, int COUT, int MODE>
DEV void conv_bn_stage(const float* __restrict__ in, const float* __restrict__ w,
                       const float* __restrict__ bias, float* __restrict__ out,
                       float* __restrict__ gate, int T, int tid,
                       float* rs, float* rq, float* stm, float* sti)
{
    float lsum[COUT], lss[COUT];
#pragma unroll
    for (int oc = 0; oc < COUT; oc++) { lsum[oc] = 0.f; lss[oc] = 0.f; }

    for (int k = 0; k < 8; k++) {
        int p = tid + k * 1024;
        int b = p / T;
        int t = p - b * T;
        float acc[COUT];
#pragma unroll
        for (int oc = 0; oc < COUT; oc++) acc[oc] = bias[oc];
#pragma unroll
        for (int ic = 0; ic < CIN; ic++) {
            const float* row = in + ((size_t)b * CIN + ic) * T;
            float xv[11];
#pragma unroll
            for (int kk = 0; kk < 11; kk++) {
                int tt = t + kk - 5;
                xv[kk] = (tt >= 0 && tt < T) ? row[tt] : 0.f;
            }
#pragma unroll
            for (int oc = 0; oc < COUT; oc++) {
                const float* wr = w + ((size_t)oc * CIN + ic) * 11;
#pragma unroll
                for (int kk = 0; kk < 11; kk++) acc[oc] += xv[kk] * wr[kk];
            }
        }
#pragma unroll
        for (int oc = 0; oc < COUT; oc++) {
            out[((size_t)b * COUT + oc) * T + t] = acc[oc];
            lsum[oc] += acc[oc];
            lss[oc] += acc[oc] * acc[oc];
        }
    }
    __syncthreads();

    int lane = tid & 63, wid = tid >> 6;
#pragma unroll
    for (int oc = 0; oc < COUT; oc++) {
        float s = lsum[oc], qq = lss[oc];
#pragma unroll
        for (int m = 32; m >= 1; m >>= 1) {
            s += __shfl_xor(s, m);
            qq += __shfl_xor(qq, m);
        }
        if (lane == 0) { rs[wid] = s; rq[wid] = qq; }
        __syncthreads();
        if (tid == 0) {
            float S = 0.f, Q = 0.f;
            for (int i = 0; i < 16; i++) { S += rs[i]; Q += rq[i]; }
            float m_ = S / (float)(2 * T);
            float v = Q / (float)(2 * T) - m_ * m_;
            stm[oc] = m_;
            sti[oc] = rsqrtf(v + 1e-5f);
        }
        __syncthreads();
    }

    for (int k = 0; k < 8; k++) {
        int p = tid + k * 1024;
        int b = p / T;
        int t = p - b * T;
#pragma unroll
        for (int oc = 0; oc < COUT; oc++) {
            size_t idx = ((size_t)b * COUT + oc) * T + t;
            float v = (out[idx] - stm[oc]) * sti[oc];
            if (MODE == 0) out[idx] = fmaxf(v, 0.f);
            else           gate[p] = sigmoidf_(v);
        }
    }
    __syncthreads();
}

__global__ __launch_bounds__(1024) void middle_kernel(
    const float* __restrict__ Hc,
    const float* __restrict__ w1, const float* __restrict__ b1,
    const float* __restrict__ w2, const float* __restrict__ b2,
    const float* __restrict__ w3, const float* __restrict__ b3,
    const float* __restrict__ w4, const float* __restrict__ b4,
    float* __restrict__ bufA, float* __restrict__ bufB,
    float* __restrict__ gate, int T)
{
    __shared__ float rs[16], rq[16], stm[8], sti[8];
    int tid = threadIdx.x;
    conv_bn_stage<3, 3, 0>(Hc,   w1, b1, bufA, nullptr, T, tid, rs, rq, stm, sti);
    conv_bn_stage<3, 5, 0>(bufA, w2, b2, bufB, nullptr, T, tid, rs, rq, stm, sti);
    conv_bn_stage<5, 5, 0>(bufB, w3, b3, bufA, nullptr, T, tid, rs, rq, stm, sti);
    conv_bn_stage<5, 1, 1>(bufA, w4, b4, bufB, gate,    T, tid, rs, rq, stm, sti);
}

// ---------------------------------------------------------------------------
// Head: y = sigmoid(fc2(fc1(out2))). One wave per (b,t).
// ---------------------------------------------------------------------------
__global__ __launch_bounds__(256) void final_kernel(
    const float* __restrict__ out2, const float* __restrict__ fc1w,
    const float* __restrict__ fc1b, const float* __restrict__ fc2w,
    const float* __restrict__ fc2b, float* __restrict__ out, int T)
{
    int wid = threadIdx.x >> 6, lane = threadIdx.x & 63;
    int bt = blockIdx.x * 4 + wid;

    const float* o2 = out2 + (size_t)bt * 64;
    float acc = fc1b[lane];
    const float* wr = fc1w + (size_t)lane * 64;
#pragma unroll
    for (int k = 0; k < 64; k++) acc += o2[k] * wr[k];

    float p = acc * fc2w[lane];
#pragma unroll
    for (int m = 32; m >= 1; m >>= 1) p += __shfl_xor(p, m);

    if (lane == 0) out[bt] = sigmoidf_(p + fc2b[0]);
}

// ---------------------------------------------------------------------------
extern "C" void kernel_launch(void* const* d_in, const int* in_sizes, int n_in,
                              void* d_out, int out_size, void* d_ws, size_t ws_size,
                              hipStream_t stream)
{
    const float* data  = (const float*)d_in[0];
    const float* h01   = (const float*)d_in[1];
    const float* c01   = (const float*)d_in[2];
    const float* h02   = (const float*)d_in[3];
    const float* c02   = (const float*)d_in[4];
    const float* Wih0  = (const float*)d_in[5];
    const float* Wih12 = (const float*)d_in[6];
    const float* l1Whh = (const float*)d_in[7];
    const float* l1b   = (const float*)d_in[8];
    const float* l2Wih = (const float*)d_in[9];
    const float* l2Whh = (const float*)d_in[10];
    const float* l2b   = (const float*)d_in[11];
    const float* cw1 = (const float*)d_in[12]; const float* cb1 = (const float*)d_in[13];
    const float* cw2 = (const float*)d_in[14]; const float* cb2 = (const float*)d_in[15];
    const float* cw3 = (const float*)d_in[16]; const float* cb3 = (const float*)d_in[17];
    const float* cw4 = (const float*)d_in[18]; const float* cb4 = (const float*)d_in[19];
    const float* fc1w = (const float*)d_in[20]; const float* fc1b = (const float*)d_in[21];
    const float* fc2w = (const float*)d_in[22]; const float* fc2b = (const float*)d_in[23];
    float* out = (float*)d_out;

    const int T = in_sizes[0] / (2 * 40);   // 4096
    const int B = 2;

    float* ws   = (float*)d_ws;
    float* xg   = ws;                                // B*T*256
    float* seqA = xg   + (size_t)B * T * 256;        // B*T*64
    float* seqB = seqA + (size_t)B * T * 64;         // B*T*64
    float* Hc   = seqB + (size_t)B * T * 64;         // B*3*T
    float* bufA = Hc   + (size_t)B * 3 * T;          // B*5*T
    float* bufB = bufA + (size_t)B * 5 * T;          // B*5*T
    float* gate = bufB + (size_t)B * 5 * T;          // B*T
    unsigned* wP = (unsigned*)(gate + (size_t)B * T); // 10*8192 u32

    dim3 pg(B * (T / 16)), pb(256);

    pack_w<<<320, 256, 0, stream>>>(l1Whh, l2Whh, Wih12, l2Wih, wP);

    // ---- LSTM1: proj layer0 + pipelined 3-layer scan ----
    proj_kernel<<<pg, pb, 0, stream>>>(data, Wih0, l1b, nullptr, xg, 40, T);
    scan3_kernel<<<2, 640, 0, stream>>>(xg, wP, wP + 6 * 8192, l1b, h01, c01, seqA, T);

    // ---- temporal-attention gate ----
    stats_kernel<<<(2 * T) / 4, 256, 0, stream>>>(seqA, Hc, T);
    middle_kernel<<<1, 1024, 0, stream>>>(Hc, cw1, cb1, cw2, cb2, cw3, cb3, cw4, cb4,
                                          bufA, bufB, gate, T);

    // ---- LSTM2: proj layer0 (gate folded) + pipelined 3-layer scan ----
    proj_kernel<<<pg, pb, 0, stream>>>(seqA, l2Wih, l2b, gate, xg, 64, T);
    scan3_kernel<<<2, 640, 0, stream>>>(xg, wP + 3 * 8192, wP + 8 * 8192, l2b, h02, c02, seqB, T);

    // ---- head ----
    final_kernel<<<(2 * T) / 4, 256, 0, stream>>>(seqB, fc1w, fc1b, fc2w, fc2b, out, T);
}